// Round 27
// baseline (73.997 us; speedup 1.0000x reference)
//
#include <hip/hip_runtime.h>

#define BB 8
#define NN 256
#define DD 128
#define SW 257  // W_msg row stride (2D+1)
#define SU 256  // W_upd row stride (2D)
#define EPSV 1e-5f
#define LOG2E 1.4426950408889634f
#define LN2F 0.6931471805599453f

typedef float v2f __attribute__((ext_vector_type(2)));

__device__ __forceinline__ float wave_reduce_add(float v) {
#pragma unroll
  for (int off = 32; off > 0; off >>= 1) v += __shfl_xor(v, off, 64);
  return v;
}

__device__ __forceinline__ float readlane_f(float v, int l) {
  return __uint_as_float(__builtin_amdgcn_readlane(__float_as_uint(v), l));
}

// ---------------- K1: centered u,s + per-row LN scalars + wtilde + WuT -----
// (unchanged, measured-best)
__global__ __launch_bounds__(256) void k_proj(
    const float* __restrict__ h, const float* __restrict__ Wm,
    const float* __restrict__ bmsg, const float* __restrict__ Wu,
    float* __restrict__ u, float* __restrict__ s,
    float* __restrict__ rowA, float* __restrict__ rowB,
    float* __restrict__ rowD2, float* __restrict__ rowE2,
    float* __restrict__ wtilv, float* __restrict__ wut) {
  const int blk = blockIdx.x;            // 512: 64 per batch, 4 rows each
  const int b = blk >> 6;
  const int r0 = (blk & 63) * 4;
  const int tid = threadIdx.x;
  const int half = tid >> 7, e = tid & 127;
  const int wv = tid >> 6, lane = tid & 63;

  __shared__ float hs[4][DD];
  __shared__ float pS[4][4], pw[2], pQ[4][4], pD[4][4];

  const float* hb = h + (size_t)(b * NN + r0) * DD;
  if (tid < DD) {
#pragma unroll
    for (int r = 0; r < 4; ++r) hs[r][e] = hb[r * DD + e];
  }
  if (tid >= DD && tid < DD + 64) {
    const int i = blk * 64 + (tid - DD);
    const int d = i >> 7, e2 = i & 127;
    wut[i] = Wu[(size_t)e2 * SU + d];
  }
  __syncthreads();

  float acc[4];
  const float bm = (half == 0) ? bmsg[e] : 0.f;   // fold b_msg into u
#pragma unroll
  for (int r = 0; r < 4; ++r) acc[r] = bm;

  const float* wr = Wm + (size_t)e * SW + half * DD;
#pragma unroll 8
  for (int k = 0; k < DD; k += 4) {
    const float4 w4 = *(const float4*)(wr + k);
#pragma unroll
    for (int r = 0; r < 4; ++r) {
      const float4 hv = *(const float4*)(&hs[r][k]);
      acc[r] = fmaf(hv.x, w4.x, acc[r]);
      acc[r] = fmaf(hv.y, w4.y, acc[r]);
      acc[r] = fmaf(hv.z, w4.z, acc[r]);
      acc[r] = fmaf(hv.w, w4.w, acc[r]);
    }
  }

  const float we = Wm[(size_t)e * SW + 2 * DD];   // wJ[e]
#pragma unroll
  for (int r = 0; r < 4; ++r) {
    const float sm = wave_reduce_add(acc[r]);
    if (lane == 0) pS[wv][r] = sm;
  }
  {
    const float sw = wave_reduce_add(we);
    if (lane == 0 && wv < 2) pw[wv] = sw;
  }
  __syncthreads();

  const int b2 = half * 2;
  const float muw = (pw[0] + pw[1]) * (1.f / DD);
  const float wtil = we - muw;
  float c[4];
#pragma unroll
  for (int r = 0; r < 4; ++r)
    c[r] = acc[r] - (pS[b2][r] + pS[b2 + 1][r]) * (1.f / DD);

  float* outp = (half == 0 ? u : s) + (size_t)(b * NN + r0) * DD;
#pragma unroll
  for (int r = 0; r < 4; ++r) outp[r * DD + e] = c[r];
  if (blk == 0 && half == 0) wtilv[e] = wtil;

#pragma unroll
  for (int r = 0; r < 4; ++r) {
    const float q = wave_reduce_add(c[r] * c[r]);
    const float dd = wave_reduce_add(c[r] * wtil);
    if (lane == 0) { pQ[wv][r] = q; pD[wv][r] = dd; }
  }
  __syncthreads();
  if (tid < 4) {
    const int row = b * NN + r0 + tid;
    rowA[row]  = pQ[0][tid] + pQ[1][tid];
    rowD2[row] = 2.f * (pD[0][tid] + pD[1][tid]);
    rowB[row]  = pQ[2][tid] + pQ[3][tid];
    rowE2[row] = 2.f * (pD[2][tid] + pD[3][tid]);
  }
}

// ---------------- K2: 2-row/block reg-resident msg+upd --------------------
// R22 base; ONLY change: silu section is PHASE-BATCHED (z-phase / exp-phase /
// rcp-phase / acc-phase separated by sched_barrier(0)). Batch arrays are
// live across the fences -> allocator must hold them -> 8 chains overlap by
// construction. Diagonal handled by mask folded into r (no branch, no tail).
__global__ __launch_bounds__(256, 4) void k_msgreg(
    const float* __restrict__ h, const float* __restrict__ u,
    const float* __restrict__ s, const float* __restrict__ adj,
    const float* __restrict__ rowA, const float* __restrict__ rowB,
    const float* __restrict__ rowD2, const float* __restrict__ rowE2,
    const float* __restrict__ wtilv, const float* __restrict__ g,
    const float* __restrict__ be, const float* __restrict__ wut,
    const float* __restrict__ bu, const float* __restrict__ gu,
    const float* __restrict__ beu, float* __restrict__ out) {
  const int blk = blockIdx.x;            // 1024 = b*128 + ip
  const int b = blk >> 7, ip = blk & 127;
  const int i0 = 2 * ip, i1 = i0 + 1;
  const int tid = threadIdx.x, lane = tid & 63, wv = tid >> 6;
  const int seg = lane & 7, jloc = lane >> 3;
  const int jrow = wv * 8 + jloc;        // this lane's j within a tile
  const int bNN = b * NN;

  __shared__ __align__(16) float upair_[2 * DD];  // centered u rows i0,i1
  __shared__ __align__(16) float hrow_[2 * DD];
  __shared__ __align__(16) float4 pakr_[NN];      // {aJ0, aJ1, Bj, E2j}
  __shared__ __align__(16) float sacc_[10 * DD];  // 8 partials + 2 agg
  __shared__ float pm[2][2], pq[2][2];

  // prologue staging (coalesced)
  {
    const int ii = tid >> 7, e = tid & 127;
    upair_[ii * DD + e] = u[(size_t)(bNN + i0 + ii) * DD + e];
    hrow_[ii * DD + e]  = h[(size_t)(bNN + i0 + ii) * DD + e];
  }
  pakr_[tid] = make_float4(adj[(size_t)(bNN + i0) * NN + tid],
                           adj[(size_t)(bNN + i1) * NN + tid],
                           rowB[bNN + tid], rowE2[bNN + tid]);
  const float2 wt2 = *(const float2*)(wtilv + 2 * lane);
  const float2 g2  = *(const float2*)(g + 2 * lane);
  const float2 be2 = *(const float2*)(be + 2 * lane);
  const v2f wt2v  = {wt2.x, wt2.y};
  const v2f gl2v  = {g2.x * LOG2E, g2.y * LOG2E};
  const v2f bel2v = {be2.x * LOG2E, be2.y * LOG2E};
  const float C = wave_reduce_add(fmaf(wt2.x, wt2.x, wt2.y * wt2.y));
  const float A0 = rowA[bNN + i0], A1 = rowA[bNN + i1];
  const float D20 = rowD2[bNN + i0], D21 = rowD2[bNN + i1];
  __syncthreads();

  const float2 uu0 = *(const float2*)(&upair_[2 * lane]);
  const float2 uu1 = *(const float2*)(&upair_[DD + 2 * lane]);
  const v2f uu0v = {uu0.x, uu0.y};
  const v2f uu1v = {uu1.x, uu1.y};
  // hoist u-segments for dots (loop-invariant)
  float4 ua[4], ub[4];
#pragma unroll
  for (int c = 0; c < 4; ++c) {
    ua[c] = *(const float4*)(&upair_[seg * 16 + c * 4]);
    ub[c] = *(const float4*)(&upair_[DD + seg * 16 + c * 4]);
  }

  const float* cA_ptr = s + (size_t)(bNN + wv * 8) * DD + 2 * lane;
  const float* sB_ptr = s + (size_t)(bNN + jrow) * DD + seg * 16;

  float2 colA[8], colB[8];               // named double buffers (static idx)
  float4 sreg[4];
  // tile-0 loads
#pragma unroll
  for (int k = 0; k < 8; ++k)
    colA[k] = *(const float2*)(cA_ptr + (size_t)k * DD);
#pragma unroll
  for (int c = 0; c < 4; ++c)
    sreg[c] = *(const float4*)(sB_ptr + c * 4);

  v2f accA = {0.f, 0.f}, accB = {0.f, 0.f};

// One tile step: dots, rs precompute, prefetch T+1, PHASE-BATCHED silu.
#define TILE_STEP(T, CUR, NXT)                                               \
  {                                                                          \
    float d0 = 0.f, d1 = 0.f;                                                \
    _Pragma("unroll")                                                        \
    for (int c = 0; c < 4; ++c) {                                            \
      d0 = fmaf(sreg[c].x, ua[c].x, d0); d0 = fmaf(sreg[c].y, ua[c].y, d0);  \
      d0 = fmaf(sreg[c].z, ua[c].z, d0); d0 = fmaf(sreg[c].w, ua[c].w, d0);  \
      d1 = fmaf(sreg[c].x, ub[c].x, d1); d1 = fmaf(sreg[c].y, ub[c].y, d1);  \
      d1 = fmaf(sreg[c].z, ub[c].z, d1); d1 = fmaf(sreg[c].w, ub[c].w, d1);  \
    }                                                                        \
    d0 += __shfl_xor(d0, 1, 64); d1 += __shfl_xor(d1, 1, 64);                \
    d0 += __shfl_xor(d0, 2, 64); d1 += __shfl_xor(d1, 2, 64);                \
    d0 += __shfl_xor(d0, 4, 64); d1 += __shfl_xor(d1, 4, 64);                \
    const int jgq = (T) * 32 + jrow;                                         \
    const float4 pk = pakr_[jgq];                                            \
    const float q0 =                                                         \
        fmaf(pk.x, fmaf(pk.x, C, D20 + pk.w), A0 + pk.z + 2.f * d0);         \
    const float q1 =                                                         \
        fmaf(pk.y, fmaf(pk.y, C, D21 + pk.w), A1 + pk.z + 2.f * d1);         \
    const float rs0v = __builtin_amdgcn_rsqf(fmaf(q0, 1.f / DD, EPSV));      \
    const float rs1v = __builtin_amdgcn_rsqf(fmaf(q1, 1.f / DD, EPSV));      \
    const float a0v = pk.x, a1v = pk.y;                                      \
    if ((T) < 7) {                                                           \
      _Pragma("unroll")                                                      \
      for (int c = 0; c < 4; ++c)                                            \
        sreg[c] =                                                            \
            *(const float4*)(sB_ptr + (size_t)((T) + 1) * 32 * DD + c * 4);  \
      _Pragma("unroll")                                                      \
      for (int k = 0; k < 8; ++k)                                            \
        NXT[k] =                                                             \
            *(const float2*)(cA_ptr + (size_t)(((T) + 1) * 32 + k) * DD);    \
    }                                                                        \
    _Pragma("unroll")                                                        \
    for (int hh = 0; hh < 2; ++hh) {                                         \
      v2f zA[4], zB[4], wA[4], wB[4];                                        \
      float mA[4], mB[4];                                                    \
      _Pragma("unroll")                                                      \
      for (int k = 0; k < 4; ++k) {                                          \
        const int kk = hh * 4 + k;                                           \
        const float rs0k = readlane_f(rs0v, kk * 8);                         \
        const float rs1k = readlane_f(rs1v, kk * 8);                         \
        const float a0k = readlane_f(a0v, kk * 8);                           \
        const float a1k = readlane_f(a1v, kk * 8);                           \
        const int jgk = (T) * 32 + wv * 8 + kk;                              \
        const float2 ss = CUR[kk];                                           \
        const v2f ssv = {ss.x, ss.y};                                        \
        zA[k] = (a0k * wt2v + (uu0v + ssv)) * (rs0k * gl2v) + bel2v;         \
        zB[k] = (a1k * wt2v + (uu1v + ssv)) * (rs1k * gl2v) + bel2v;         \
        mA[k] = (jgk != i0) ? 1.f : 0.f;                                     \
        mB[k] = (jgk != i1) ? 1.f : 0.f;                                     \
      }                                                                      \
      __builtin_amdgcn_sched_barrier(0);                                     \
      float eA0[4], eA1[4], eB0[4], eB1[4];                                  \
      _Pragma("unroll")                                                      \
      for (int k = 0; k < 4; ++k) {                                          \
        eA0[k] = exp2f(-zA[k].x); eA1[k] = exp2f(-zA[k].y);                  \
        eB0[k] = exp2f(-zB[k].x); eB1[k] = exp2f(-zB[k].y);                  \
      }                                                                      \
      __builtin_amdgcn_sched_barrier(0);                                     \
      _Pragma("unroll")                                                      \
      for (int k = 0; k < 4; ++k) {                                          \
        const float pA0 = 1.f + eA0[k], pA1 = 1.f + eA1[k];                  \
        const float rA = __builtin_amdgcn_rcpf(pA0 * pA1) * mA[k];           \
        wA[k] = (v2f){rA * pA1, rA * pA0};                                   \
        const float pB0 = 1.f + eB0[k], pB1 = 1.f + eB1[k];                  \
        const float rB = __builtin_amdgcn_rcpf(pB0 * pB1) * mB[k];           \
        wB[k] = (v2f){rB * pB1, rB * pB0};                                   \
      }                                                                      \
      __builtin_amdgcn_sched_barrier(0);                                     \
      _Pragma("unroll")                                                      \
      for (int k = 0; k < 4; ++k) {                                          \
        accA = zA[k] * wA[k] + accA;                                         \
        accB = zB[k] * wB[k] + accB;                                         \
      }                                                                      \
    }                                                                        \
  }

#pragma unroll 1
  for (int tt = 0; tt < 8; tt += 2) {
    TILE_STEP(tt, colA, colB);
    TILE_STEP(tt + 1, colB, colA);
  }
#undef TILE_STEP

  // ---- reduce 4 waves -> agg rows (LN2 fold applied here) ----
  *(float2*)(&sacc_[(wv * 2 + 0) * DD + 2 * lane]) =
      make_float2(accA.x * LN2F, accA.y * LN2F);
  *(float2*)(&sacc_[(wv * 2 + 1) * DD + 2 * lane]) =
      make_float2(accB.x * LN2F, accB.y * LN2F);
  __syncthreads();
  {
    const int ii = tid >> 7, e = tid & 127;
    sacc_[(8 + ii) * DD + e] = sacc_[(0 + ii) * DD + e] +
                               sacc_[(2 + ii) * DD + e] +
                               sacc_[(4 + ii) * DD + e] +
                               sacc_[(6 + ii) * DD + e];
  }
  __syncthreads();

  // ---- upd tail (unchanged) ----
  const int half = tid >> 7, e = tid & 127;
  float v0 = (half == 0) ? bu[e] : 0.f;
  float v1 = v0;
  {
    const float* xin = (half == 0) ? hrow_ : &sacc_[8 * DD];
    const float* wcol = wut + (size_t)half * DD * DD + e;
#pragma unroll 8
    for (int k = 0; k < DD; ++k) {
      const float w = wcol[(size_t)k * DD];
      v0 = fmaf(xin[k], w, v0);
      v1 = fmaf(xin[DD + k], w, v1);
    }
  }
  if (half == 1) { upair_[e] = v0; upair_[DD + e] = v1; }  // comb
  __syncthreads();
  if (half == 0) {
    v0 += upair_[e];
    v1 += upair_[DD + e];
    const float sm0 = wave_reduce_add(v0), sq0 = wave_reduce_add(v0 * v0);
    const float sm1 = wave_reduce_add(v1), sq1 = wave_reduce_add(v1 * v1);
    if (lane == 0) {
      pm[wv][0] = sm0; pq[wv][0] = sq0;
      pm[wv][1] = sm1; pq[wv][1] = sq1;
    }
  }
  __syncthreads();
  if (half == 0) {
    const float ge = gu[e], bee = beu[e];
    {
      const float mean = (pm[0][0] + pm[1][0]) * (1.f / DD);
      const float var = (pq[0][0] + pq[1][0]) * (1.f / DD) - mean * mean;
      const float rs = __builtin_amdgcn_rsqf(var + EPSV);
      const float y = fmaf((v0 - mean) * rs, ge, bee);
      const float sg = __builtin_amdgcn_rcpf(1.f + __expf(-y));
      out[(size_t)(bNN + i0) * DD + e] = hrow_[e] + y * sg;
    }
    {
      const float mean = (pm[0][1] + pm[1][1]) * (1.f / DD);
      const float var = (pq[0][1] + pq[1][1]) * (1.f / DD) - mean * mean;
      const float rs = __builtin_amdgcn_rsqf(var + EPSV);
      const float y = fmaf((v1 - mean) * rs, ge, bee);
      const float sg = __builtin_amdgcn_rcpf(1.f + __expf(-y));
      out[(size_t)(bNN + i1) * DD + e] = hrow_[DD + e] + y * sg;
    }
  }
}

extern "C" void kernel_launch(void* const* d_in, const int* in_sizes, int n_in,
                              void* d_out, int out_size, void* d_ws, size_t ws_size,
                              hipStream_t stream) {
  const float* h    = (const float*)d_in[0];
  const float* adj  = (const float*)d_in[1];
  const float* Wm   = (const float*)d_in[2];
  const float* bmsg = (const float*)d_in[3];
  const float* gmsg = (const float*)d_in[4];
  const float* bemsg= (const float*)d_in[5];
  const float* Wu   = (const float*)d_in[6];
  const float* bupd = (const float*)d_in[7];
  const float* gupd = (const float*)d_in[8];
  const float* beupd= (const float*)d_in[9];
  float* out = (float*)d_out;

  float* ws    = (float*)d_ws;
  float* u     = ws;                        // 262144
  float* s     = u + BB * NN * DD;          // 262144
  float* rowA  = s + BB * NN * DD;          // 2048
  float* rowB  = rowA + BB * NN;            // 2048
  float* rowD2 = rowB + BB * NN;            // 2048
  float* rowE2 = rowD2 + BB * NN;           // 2048
  float* wtilv = rowE2 + BB * NN;           // 128
  float* wut   = wtilv + DD;                // 32768

  k_proj<<<512, 256, 0, stream>>>(h, Wm, bmsg, Wu, u, s, rowA, rowB, rowD2,
                                  rowE2, wtilv, wut);
  k_msgreg<<<1024, 256, 0, stream>>>(h, u, s, adj, rowA, rowB, rowD2, rowE2,
                                     wtilv, gmsg, bemsg, wut, bupd, gupd,
                                     beupd, out);
}

// Round 28
// 54.048 us; speedup vs baseline: 1.3691x; 1.3691x over previous
//
#include <hip/hip_runtime.h>

#define BB 8
#define NN 256
#define DD 128
#define SW 257  // W_msg row stride (2D+1)
#define SU 256  // W_upd row stride (2D)
#define EPSV 1e-5f
#define LOG2E 1.4426950408889634f
#define LN2F 0.6931471805599453f

typedef float v2f __attribute__((ext_vector_type(2)));

__device__ __forceinline__ float wave_reduce_add(float v) {
#pragma unroll
  for (int off = 32; off > 0; off >>= 1) v += __shfl_xor(v, off, 64);
  return v;
}

__device__ __forceinline__ float readlane_f(float v, int l) {
  return __uint_as_float(__builtin_amdgcn_readlane(__float_as_uint(v), l));
}

// ---------------- K1: centered u,s + per-row LN scalars + wtilde + WuT -----
// (measured-best)
__global__ __launch_bounds__(256) void k_proj(
    const float* __restrict__ h, const float* __restrict__ Wm,
    const float* __restrict__ bmsg, const float* __restrict__ Wu,
    float* __restrict__ u, float* __restrict__ s,
    float* __restrict__ rowA, float* __restrict__ rowB,
    float* __restrict__ rowD2, float* __restrict__ rowE2,
    float* __restrict__ wtilv, float* __restrict__ wut) {
  const int blk = blockIdx.x;            // 512: 64 per batch, 4 rows each
  const int b = blk >> 6;
  const int r0 = (blk & 63) * 4;
  const int tid = threadIdx.x;
  const int half = tid >> 7, e = tid & 127;
  const int wv = tid >> 6, lane = tid & 63;

  __shared__ float hs[4][DD];
  __shared__ float pS[4][4], pw[2], pQ[4][4], pD[4][4];

  const float* hb = h + (size_t)(b * NN + r0) * DD;
  if (tid < DD) {
#pragma unroll
    for (int r = 0; r < 4; ++r) hs[r][e] = hb[r * DD + e];
  }
  if (tid >= DD && tid < DD + 64) {
    const int i = blk * 64 + (tid - DD);
    const int d = i >> 7, e2 = i & 127;
    wut[i] = Wu[(size_t)e2 * SU + d];
  }
  __syncthreads();

  float acc[4];
  const float bm = (half == 0) ? bmsg[e] : 0.f;   // fold b_msg into u
#pragma unroll
  for (int r = 0; r < 4; ++r) acc[r] = bm;

  const float* wr = Wm + (size_t)e * SW + half * DD;
#pragma unroll 8
  for (int k = 0; k < DD; k += 4) {
    const float4 w4 = *(const float4*)(wr + k);
#pragma unroll
    for (int r = 0; r < 4; ++r) {
      const float4 hv = *(const float4*)(&hs[r][k]);
      acc[r] = fmaf(hv.x, w4.x, acc[r]);
      acc[r] = fmaf(hv.y, w4.y, acc[r]);
      acc[r] = fmaf(hv.z, w4.z, acc[r]);
      acc[r] = fmaf(hv.w, w4.w, acc[r]);
    }
  }

  const float we = Wm[(size_t)e * SW + 2 * DD];   // wJ[e]
#pragma unroll
  for (int r = 0; r < 4; ++r) {
    const float sm = wave_reduce_add(acc[r]);
    if (lane == 0) pS[wv][r] = sm;
  }
  {
    const float sw = wave_reduce_add(we);
    if (lane == 0 && wv < 2) pw[wv] = sw;
  }
  __syncthreads();

  const int b2 = half * 2;
  const float muw = (pw[0] + pw[1]) * (1.f / DD);
  const float wtil = we - muw;
  float c[4];
#pragma unroll
  for (int r = 0; r < 4; ++r)
    c[r] = acc[r] - (pS[b2][r] + pS[b2 + 1][r]) * (1.f / DD);

  float* outp = (half == 0 ? u : s) + (size_t)(b * NN + r0) * DD;
#pragma unroll
  for (int r = 0; r < 4; ++r) outp[r * DD + e] = c[r];
  if (blk == 0 && half == 0) wtilv[e] = wtil;

#pragma unroll
  for (int r = 0; r < 4; ++r) {
    const float q = wave_reduce_add(c[r] * c[r]);
    const float dd = wave_reduce_add(c[r] * wtil);
    if (lane == 0) { pQ[wv][r] = q; pD[wv][r] = dd; }
  }
  __syncthreads();
  if (tid < 4) {
    const int row = b * NN + r0 + tid;
    rowA[row]  = pQ[0][tid] + pQ[1][tid];
    rowD2[row] = 2.f * (pD[0][tid] + pD[1][tid]);
    rowB[row]  = pQ[2][tid] + pQ[3][tid];
    rowE2[row] = 2.f * (pD[2][tid] + pD[3][tid]);
  }
}

// ---------------- K2: 2-row/block reg-resident msg+upd (measured best) ----
// Partial-unroll tile loop (2 steps/iter, named double buffers), readlane
// broadcasts, packed f32 silu, paired rcp. 54.1 us total, absmax 0.0078.
__global__ __launch_bounds__(256, 4) void k_msgreg(
    const float* __restrict__ h, const float* __restrict__ u,
    const float* __restrict__ s, const float* __restrict__ adj,
    const float* __restrict__ rowA, const float* __restrict__ rowB,
    const float* __restrict__ rowD2, const float* __restrict__ rowE2,
    const float* __restrict__ wtilv, const float* __restrict__ g,
    const float* __restrict__ be, const float* __restrict__ wut,
    const float* __restrict__ bu, const float* __restrict__ gu,
    const float* __restrict__ beu, float* __restrict__ out) {
  const int blk = blockIdx.x;            // 1024 = b*128 + ip
  const int b = blk >> 7, ip = blk & 127;
  const int i0 = 2 * ip, i1 = i0 + 1;
  const int tid = threadIdx.x, lane = tid & 63, wv = tid >> 6;
  const int seg = lane & 7, jloc = lane >> 3;
  const int jrow = wv * 8 + jloc;        // this lane's j within a tile
  const int bNN = b * NN;

  __shared__ __align__(16) float upair_[2 * DD];  // centered u rows i0,i1
  __shared__ __align__(16) float hrow_[2 * DD];
  __shared__ __align__(16) float4 pakr_[NN];      // {aJ0, aJ1, Bj, E2j}
  __shared__ __align__(16) float sacc_[10 * DD];  // 8 partials + 2 agg
  __shared__ float pm[2][2], pq[2][2];

  // prologue staging (coalesced)
  {
    const int ii = tid >> 7, e = tid & 127;
    upair_[ii * DD + e] = u[(size_t)(bNN + i0 + ii) * DD + e];
    hrow_[ii * DD + e]  = h[(size_t)(bNN + i0 + ii) * DD + e];
  }
  pakr_[tid] = make_float4(adj[(size_t)(bNN + i0) * NN + tid],
                           adj[(size_t)(bNN + i1) * NN + tid],
                           rowB[bNN + tid], rowE2[bNN + tid]);
  const float2 wt2 = *(const float2*)(wtilv + 2 * lane);
  const float2 g2  = *(const float2*)(g + 2 * lane);
  const float2 be2 = *(const float2*)(be + 2 * lane);
  const v2f wt2v  = {wt2.x, wt2.y};
  const v2f gl2v  = {g2.x * LOG2E, g2.y * LOG2E};
  const v2f bel2v = {be2.x * LOG2E, be2.y * LOG2E};
  const float C = wave_reduce_add(fmaf(wt2.x, wt2.x, wt2.y * wt2.y));
  const float A0 = rowA[bNN + i0], A1 = rowA[bNN + i1];
  const float D20 = rowD2[bNN + i0], D21 = rowD2[bNN + i1];
  __syncthreads();

  const float2 uu0 = *(const float2*)(&upair_[2 * lane]);
  const float2 uu1 = *(const float2*)(&upair_[DD + 2 * lane]);
  const v2f uu0v = {uu0.x, uu0.y};
  const v2f uu1v = {uu1.x, uu1.y};
  // hoist u-segments for dots (loop-invariant)
  float4 ua[4], ub[4];
#pragma unroll
  for (int c = 0; c < 4; ++c) {
    ua[c] = *(const float4*)(&upair_[seg * 16 + c * 4]);
    ub[c] = *(const float4*)(&upair_[DD + seg * 16 + c * 4]);
  }

  const float* cA_ptr = s + (size_t)(bNN + wv * 8) * DD + 2 * lane;
  const float* sB_ptr = s + (size_t)(bNN + jrow) * DD + seg * 16;

  float2 colA[8], colB[8];               // named double buffers (static idx)
  float4 sreg[4];
  // tile-0 loads
#pragma unroll
  for (int k = 0; k < 8; ++k)
    colA[k] = *(const float2*)(cA_ptr + (size_t)k * DD);
#pragma unroll
  for (int c = 0; c < 4; ++c)
    sreg[c] = *(const float4*)(sB_ptr + c * 4);

  v2f accA = {0.f, 0.f}, accB = {0.f, 0.f};

// One tile step: dots from sreg, rs precompute, prefetch T+1 into NXT/sreg,
// branchy packed silu from CUR. All inner loops unrolled; T is runtime.
#define TILE_STEP(T, CUR, NXT)                                               \
  {                                                                          \
    float d0 = 0.f, d1 = 0.f;                                                \
    _Pragma("unroll")                                                        \
    for (int c = 0; c < 4; ++c) {                                            \
      d0 = fmaf(sreg[c].x, ua[c].x, d0); d0 = fmaf(sreg[c].y, ua[c].y, d0);  \
      d0 = fmaf(sreg[c].z, ua[c].z, d0); d0 = fmaf(sreg[c].w, ua[c].w, d0);  \
      d1 = fmaf(sreg[c].x, ub[c].x, d1); d1 = fmaf(sreg[c].y, ub[c].y, d1);  \
      d1 = fmaf(sreg[c].z, ub[c].z, d1); d1 = fmaf(sreg[c].w, ub[c].w, d1);  \
    }                                                                        \
    d0 += __shfl_xor(d0, 1, 64); d1 += __shfl_xor(d1, 1, 64);                \
    d0 += __shfl_xor(d0, 2, 64); d1 += __shfl_xor(d1, 2, 64);                \
    d0 += __shfl_xor(d0, 4, 64); d1 += __shfl_xor(d1, 4, 64);                \
    const int jgq = (T) * 32 + jrow;                                         \
    const float4 pk = pakr_[jgq];                                            \
    const float q0 =                                                         \
        fmaf(pk.x, fmaf(pk.x, C, D20 + pk.w), A0 + pk.z + 2.f * d0);         \
    const float q1 =                                                         \
        fmaf(pk.y, fmaf(pk.y, C, D21 + pk.w), A1 + pk.z + 2.f * d1);         \
    const float rs0v = __builtin_amdgcn_rsqf(fmaf(q0, 1.f / DD, EPSV));      \
    const float rs1v = __builtin_amdgcn_rsqf(fmaf(q1, 1.f / DD, EPSV));      \
    const float a0v = pk.x, a1v = pk.y;                                      \
    if ((T) < 7) {                                                           \
      _Pragma("unroll")                                                      \
      for (int c = 0; c < 4; ++c)                                            \
        sreg[c] =                                                            \
            *(const float4*)(sB_ptr + (size_t)((T) + 1) * 32 * DD + c * 4);  \
      _Pragma("unroll")                                                      \
      for (int k = 0; k < 8; ++k)                                            \
        NXT[k] =                                                             \
            *(const float2*)(cA_ptr + (size_t)(((T) + 1) * 32 + k) * DD);    \
    }                                                                        \
    _Pragma("unroll")                                                        \
    for (int k = 0; k < 8; ++k) {                                            \
      const float rs0k = readlane_f(rs0v, k * 8);                            \
      const float rs1k = readlane_f(rs1v, k * 8);                            \
      const float a0k = readlane_f(a0v, k * 8);                              \
      const float a1k = readlane_f(a1v, k * 8);                              \
      const int jgk = (T) * 32 + wv * 8 + k;                                 \
      const float2 ss = CUR[k];                                              \
      const v2f ssv = {ss.x, ss.y};                                          \
      const v2f sAv = uu0v + ssv;                                            \
      const v2f sBv = uu1v + ssv;                                            \
      if (jgk != i0) {                                                       \
        const v2f x = a0k * wt2v + sAv;                                      \
        const v2f rg = rs0k * gl2v;                                          \
        const v2f z = x * rg + bel2v;                                        \
        const float e0 = exp2f(-z.x), e1 = exp2f(-z.y);                      \
        const float p0 = 1.f + e0, p1 = 1.f + e1;                            \
        const float r = __builtin_amdgcn_rcpf(p0 * p1);                      \
        const v2f w = {r * p1, r * p0};                                      \
        accA = z * w + accA;                                                 \
      }                                                                      \
      if (jgk != i1) {                                                       \
        const v2f x = a1k * wt2v + sBv;                                      \
        const v2f rg = rs1k * gl2v;                                          \
        const v2f z = x * rg + bel2v;                                        \
        const float e0 = exp2f(-z.x), e1 = exp2f(-z.y);                      \
        const float p0 = 1.f + e0, p1 = 1.f + e1;                            \
        const float r = __builtin_amdgcn_rcpf(p0 * p1);                      \
        const v2f w = {r * p1, r * p0};                                      \
        accB = z * w + accB;                                                 \
      }                                                                      \
    }                                                                        \
  }

#pragma unroll 1
  for (int tt = 0; tt < 8; tt += 2) {
    TILE_STEP(tt, colA, colB);
    TILE_STEP(tt + 1, colB, colA);
  }
#undef TILE_STEP

  // ---- reduce 4 waves -> agg rows (LN2 fold applied here) ----
  *(float2*)(&sacc_[(wv * 2 + 0) * DD + 2 * lane]) =
      make_float2(accA.x * LN2F, accA.y * LN2F);
  *(float2*)(&sacc_[(wv * 2 + 1) * DD + 2 * lane]) =
      make_float2(accB.x * LN2F, accB.y * LN2F);
  __syncthreads();
  {
    const int ii = tid >> 7, e = tid & 127;
    sacc_[(8 + ii) * DD + e] = sacc_[(0 + ii) * DD + e] +
                               sacc_[(2 + ii) * DD + e] +
                               sacc_[(4 + ii) * DD + e] +
                               sacc_[(6 + ii) * DD + e];
  }
  __syncthreads();

  // ---- upd tail ----
  const int half = tid >> 7, e = tid & 127;
  float v0 = (half == 0) ? bu[e] : 0.f;
  float v1 = v0;
  {
    const float* xin = (half == 0) ? hrow_ : &sacc_[8 * DD];
    const float* wcol = wut + (size_t)half * DD * DD + e;
#pragma unroll 8
    for (int k = 0; k < DD; ++k) {
      const float w = wcol[(size_t)k * DD];
      v0 = fmaf(xin[k], w, v0);
      v1 = fmaf(xin[DD + k], w, v1);
    }
  }
  if (half == 1) { upair_[e] = v0; upair_[DD + e] = v1; }  // comb
  __syncthreads();
  if (half == 0) {
    v0 += upair_[e];
    v1 += upair_[DD + e];
    const float sm0 = wave_reduce_add(v0), sq0 = wave_reduce_add(v0 * v0);
    const float sm1 = wave_reduce_add(v1), sq1 = wave_reduce_add(v1 * v1);
    if (lane == 0) {
      pm[wv][0] = sm0; pq[wv][0] = sq0;
      pm[wv][1] = sm1; pq[wv][1] = sq1;
    }
  }
  __syncthreads();
  if (half == 0) {
    const float ge = gu[e], bee = beu[e];
    {
      const float mean = (pm[0][0] + pm[1][0]) * (1.f / DD);
      const float var = (pq[0][0] + pq[1][0]) * (1.f / DD) - mean * mean;
      const float rs = __builtin_amdgcn_rsqf(var + EPSV);
      const float y = fmaf((v0 - mean) * rs, ge, bee);
      const float sg = __builtin_amdgcn_rcpf(1.f + __expf(-y));
      out[(size_t)(bNN + i0) * DD + e] = hrow_[e] + y * sg;
    }
    {
      const float mean = (pm[0][1] + pm[1][1]) * (1.f / DD);
      const float var = (pq[0][1] + pq[1][1]) * (1.f / DD) - mean * mean;
      const float rs = __builtin_amdgcn_rsqf(var + EPSV);
      const float y = fmaf((v1 - mean) * rs, ge, bee);
      const float sg = __builtin_amdgcn_rcpf(1.f + __expf(-y));
      out[(size_t)(bNN + i1) * DD + e] = hrow_[DD + e] + y * sg;
    }
  }
}

extern "C" void kernel_launch(void* const* d_in, const int* in_sizes, int n_in,
                              void* d_out, int out_size, void* d_ws, size_t ws_size,
                              hipStream_t stream) {
  const float* h    = (const float*)d_in[0];
  const float* adj  = (const float*)d_in[1];
  const float* Wm   = (const float*)d_in[2];
  const float* bmsg = (const float*)d_in[3];
  const float* gmsg = (const float*)d_in[4];
  const float* bemsg= (const float*)d_in[5];
  const float* Wu   = (const float*)d_in[6];
  const float* bupd = (const float*)d_in[7];
  const float* gupd = (const float*)d_in[8];
  const float* beupd= (const float*)d_in[9];
  float* out = (float*)d_out;

  float* ws    = (float*)d_ws;
  float* u     = ws;                        // 262144
  float* s     = u + BB * NN * DD;          // 262144
  float* rowA  = s + BB * NN * DD;          // 2048
  float* rowB  = rowA + BB * NN;            // 2048
  float* rowD2 = rowB + BB * NN;            // 2048
  float* rowE2 = rowD2 + BB * NN;           // 2048
  float* wtilv = rowE2 + BB * NN;           // 128
  float* wut   = wtilv + DD;                // 32768

  k_proj<<<512, 256, 0, stream>>>(h, Wm, bmsg, Wu, u, s, rowA, rowB, rowD2,
                                  rowE2, wtilv, wut);
  k_msgreg<<<1024, 256, 0, stream>>>(h, u, s, adj, rowA, rowB, rowD2, rowE2,
                                     wtilv, gmsg, bemsg, wut, bupd, gupd,
                                     beupd, out);
}